// Round 19
// baseline (193.509 us; speedup 1.0000x reference)
//
#include <hip/hip_runtime.h>
#include <hip/hip_bf16.h>

typedef __bf16 bf16x8 __attribute__((ext_vector_type(8)));
typedef float f32x4 __attribute__((ext_vector_type(4)));
typedef float f32x16 __attribute__((ext_vector_type(16)));

__device__ __forceinline__ ushort f2bf(float f) {
  union { float f; unsigned u; } x; x.f = f;
  unsigned r = x.u + 0x7fffu + ((x.u >> 16) & 1u);
  return (ushort)(r >> 16);
}

__device__ __forceinline__ void gld_lds16(const void* g, void* l) {
  __builtin_amdgcn_global_load_lds(
      (const __attribute__((address_space(1))) void*)g,
      (__attribute__((address_space(3))) void*)l, 16, 0, 0);
}

#define VMW1   asm volatile("s_waitcnt vmcnt(1)" ::: "memory")
#define VMW2   asm volatile("s_waitcnt vmcnt(2)" ::: "memory")
#define VMW4   asm volatile("s_waitcnt vmcnt(4)" ::: "memory")
#define VMW0   asm volatile("s_waitcnt vmcnt(0)" ::: "memory")
#define LGKM0  asm volatile("s_waitcnt lgkmcnt(0)" ::: "memory")
#define SCHEDB __builtin_amdgcn_sched_barrier(0)
#define RBAR   __builtin_amdgcn_s_barrier()

// ---------------- f32 -> bf16 convert (weights only) ----------------
__global__ __launch_bounds__(256) void k_cvt_w(
    const float* __restrict__ wi, const float* __restrict__ wo,
    ushort* __restrict__ dst) {
  const int NWI = 196608, NWO = 65536;   // float4 counts
  const int total = NWI + NWO;
  int i = blockIdx.x * 256 + threadIdx.x;
  int stride = gridDim.x * 256;
  for (; i < total; i += stride) {
    const float* s; int j;
    if (i < NWI) { s = wi; j = i; }
    else         { s = wo; j = i - NWI; }
    float4 val = reinterpret_cast<const float4*>(s)[j];
    ushort4 o;
    o.x = f2bf(val.x); o.y = f2bf(val.y); o.z = f2bf(val.z); o.w = f2bf(val.w);
    reinterpret_cast<ushort4*>(dst)[i] = o;
  }
}

// ---------------- QKV GEMM (R13: fused cvt, 3-buffer B, counted vmcnt) -----
__global__ __launch_bounds__(256) void k_gemm_qkv(
    const float* __restrict__ za0, const float* __restrict__ za1,
    const float* __restrict__ za2,
    const ushort* __restrict__ Btbase,
    const float* __restrict__ biasbase,
    ushort* __restrict__ Cbase, float qs)
{
  int bid0 = blockIdx.x;
  int bid = (bid0 & 7) * 96 + (bid0 >> 3);   // XCD-chunked, 768 % 8 == 0
  int yy = bid & 3;
  int rest = bid >> 2;
  int xx = rest & 63;
  int z = rest >> 6;

  const float* A32 = (z == 0) ? za0 : (z == 1) ? za1 : za2;
  const ushort* Bt = Btbase + (size_t)262144 * z;
  const float* bias = biasbase + 512 * z;
  float osc = (z == 0) ? qs : 1.0f;

  __shared__ ushort As[2][4096];
  __shared__ ushort Bs[3][4096];

  int tid = threadIdx.x;
  int wv = tid >> 6, ln = tid & 63;
  int l15 = ln & 15, lg = ln >> 4;
  int wm = wv >> 1, wn = wv & 1;
  int m0 = xx * 128, n0 = yy * 128;

  int row_s = tid >> 1, kh = (tid & 1) * 16;
  const float* aP = A32 + (size_t)(m0 + row_s) * 512 + kh;
  int ldsOff = row_s * 32 + kh;

#define STAGE_B(KT, BUF)                                                      \
  {                                                                           \
    _Pragma("unroll")                                                         \
    for (int h2 = 0; h2 < 2; ++h2) {                                          \
      int c = h2 * 256 + wv * 64 + ln;                                        \
      int row = c >> 2, kc = (c & 3) * 8;                                     \
      gld_lds16(Bt + (size_t)(n0 + row) * 512 + (KT) * 32 + kc,               \
                (char*)&Bs[BUF][0] + (h2 * 256 + wv * 64) * 16);              \
    }                                                                         \
  }

#define CVT_WRITE_A(F0, F1, F2, F3, BUF)                                      \
  {                                                                           \
    uint w0, w1, w2, w3, w4, w5, w6, w7;                                      \
    asm("v_cvt_pk_bf16_f32 %0, %1, %2" : "=v"(w0) : "v"(F0.x), "v"(F0.y));    \
    asm("v_cvt_pk_bf16_f32 %0, %1, %2" : "=v"(w1) : "v"(F0.z), "v"(F0.w));    \
    asm("v_cvt_pk_bf16_f32 %0, %1, %2" : "=v"(w2) : "v"(F1.x), "v"(F1.y));    \
    asm("v_cvt_pk_bf16_f32 %0, %1, %2" : "=v"(w3) : "v"(F1.z), "v"(F1.w));    \
    asm("v_cvt_pk_bf16_f32 %0, %1, %2" : "=v"(w4) : "v"(F2.x), "v"(F2.y));    \
    asm("v_cvt_pk_bf16_f32 %0, %1, %2" : "=v"(w5) : "v"(F2.z), "v"(F2.w));    \
    asm("v_cvt_pk_bf16_f32 %0, %1, %2" : "=v"(w6) : "v"(F3.x), "v"(F3.y));    \
    asm("v_cvt_pk_bf16_f32 %0, %1, %2" : "=v"(w7) : "v"(F3.z), "v"(F3.w));    \
    uint4 p0; p0.x = w0; p0.y = w1; p0.z = w2; p0.w = w3;                     \
    uint4 p1; p1.x = w4; p1.y = w5; p1.z = w6; p1.w = w7;                     \
    reinterpret_cast<uint4*>(&As[BUF][ldsOff])[0] = p0;                       \
    reinterpret_cast<uint4*>(&As[BUF][ldsOff + 8])[0] = p1;                   \
  }

  f32x4 acc[4][4] = {};

  STAGE_B(0, 0);
  float4 g0 = reinterpret_cast<const float4*>(aP)[0];
  float4 g1 = reinterpret_cast<const float4*>(aP)[1];
  float4 g2 = reinterpret_cast<const float4*>(aP)[2];
  float4 g3 = reinterpret_cast<const float4*>(aP)[3];
  STAGE_B(1, 1);
  VMW2; SCHEDB;
  CVT_WRITE_A(g0, g1, g2, g3, 0);
  LGKM0; SCHEDB;
  RBAR;

#pragma unroll
  for (int kt = 0; kt < 16; ++kt) {
    const int cur = kt & 1;
    const int bcur = kt % 3;
    float4 f0, f1, f2, f3;
    if (kt < 15) {
      const float* ap = aP + (kt + 1) * 32;
      f0 = reinterpret_cast<const float4*>(ap)[0];
      f1 = reinterpret_cast<const float4*>(ap)[1];
      f2 = reinterpret_cast<const float4*>(ap)[2];
      f3 = reinterpret_cast<const float4*>(ap)[3];
    }
    if (kt < 14) STAGE_B(kt + 2, (kt + 2) % 3);

    bf16x8 af[4], bf4[4];
#pragma unroll
    for (int mf = 0; mf < 4; ++mf)
      af[mf] = *reinterpret_cast<const bf16x8*>(&As[cur][(wm * 64 + mf * 16 + l15) * 32 + lg * 8]);
#pragma unroll
    for (int nf = 0; nf < 4; ++nf)
      bf4[nf] = *reinterpret_cast<const bf16x8*>(&Bs[bcur][(wn * 64 + nf * 16 + l15) * 32 + lg * 8]);
#pragma unroll
    for (int mf = 0; mf < 4; ++mf)
#pragma unroll
      for (int nf = 0; nf < 4; ++nf)
        acc[mf][nf] = __builtin_amdgcn_mfma_f32_16x16x32_bf16(af[mf], bf4[nf], acc[mf][nf], 0, 0, 0);

    if (kt < 15) {
      if (kt < 14) { VMW2; } else { VMW0; }
      SCHEDB;
      CVT_WRITE_A(f0, f1, f2, f3, cur ^ 1);
      LGKM0; SCHEDB;
      RBAR;
    }
  }

#pragma unroll
  for (int mf = 0; mf < 4; ++mf)
#pragma unroll
    for (int nf = 0; nf < 4; ++nf)
#pragma unroll
      for (int r = 0; r < 4; ++r) {
        int rr = m0 + wm * 64 + mf * 16 + lg * 4 + r;
        int cc = n0 + wn * 64 + nf * 16 + l15;
        float v = (acc[mf][nf][r] + bias[cc]) * osc;
        (Cbase + (size_t)4194304 * z)[(size_t)rr * 512 + cc] = f2bf(v);
      }
#undef STAGE_B
#undef CVT_WRITE_A
}

// ---------------- out-proj GEMM (R13, unchanged) ----------------
__global__ __launch_bounds__(256) void k_gemm_out(
    const ushort* __restrict__ Ab, const ushort* __restrict__ Bt,
    const float* __restrict__ bias, float* __restrict__ C)
{
  int bid0 = blockIdx.x;
  int bid = (bid0 & 7) * 60 + (bid0 >> 3);   // XCD-chunked, 480 % 8 == 0
  int yy = bid & 3;
  int xx = bid >> 2;

  __shared__ ushort As[3][4096];
  __shared__ ushort Bs[3][4096];

  int tid = threadIdx.x;
  int wv = tid >> 6, ln = tid & 63;
  int l15 = ln & 15, lg = ln >> 4;
  int wm = wv >> 1, wn = wv & 1;
  int m0 = xx * 128, n0 = yy * 128;

#define STAGE_AB(KT, BUF)                                                     \
  {                                                                           \
    _Pragma("unroll")                                                         \
    for (int h2 = 0; h2 < 2; ++h2) {                                          \
      int c = h2 * 256 + wv * 64 + ln;                                        \
      int row = c >> 2, kc = (c & 3) * 8;                                     \
      gld_lds16(Ab + (size_t)(m0 + row) * 512 + (KT) * 32 + kc,               \
                (char*)&As[BUF][0] + (h2 * 256 + wv * 64) * 16);              \
      gld_lds16(Bt + (size_t)(n0 + row) * 512 + (KT) * 32 + kc,               \
                (char*)&Bs[BUF][0] + (h2 * 256 + wv * 64) * 16);              \
    }                                                                         \
  }

  f32x4 acc[4][4] = {};

  STAGE_AB(0, 0);
  STAGE_AB(1, 1);
  VMW4; SCHEDB;
  RBAR;

#pragma unroll
  for (int kt = 0; kt < 16; ++kt) {
    const int bcur = kt % 3;
    if (kt < 14) STAGE_AB(kt + 2, (kt + 2) % 3);

    bf16x8 af[4], bf4[4];
#pragma unroll
    for (int mf = 0; mf < 4; ++mf)
      af[mf] = *reinterpret_cast<const bf16x8*>(&As[bcur][(wm * 64 + mf * 16 + l15) * 32 + lg * 8]);
#pragma unroll
    for (int nf = 0; nf < 4; ++nf)
      bf4[nf] = *reinterpret_cast<const bf16x8*>(&Bs[bcur][(wn * 64 + nf * 16 + l15) * 32 + lg * 8]);
#pragma unroll
    for (int mf = 0; mf < 4; ++mf)
#pragma unroll
      for (int nf = 0; nf < 4; ++nf)
        acc[mf][nf] = __builtin_amdgcn_mfma_f32_16x16x32_bf16(af[mf], bf4[nf], acc[mf][nf], 0, 0, 0);

    if (kt < 15) {
      if (kt < 14) { VMW4; } else { VMW0; }
      SCHEDB;
      RBAR;
    }
  }

#pragma unroll
  for (int mf = 0; mf < 4; ++mf)
#pragma unroll
    for (int nf = 0; nf < 4; ++nf)
#pragma unroll
      for (int r = 0; r < 4; ++r) {
        int rr = m0 + wm * 64 + mf * 16 + lg * 4 + r;
        int cc = n0 + wn * 64 + nf * 16 + l15;
        C[(size_t)rr * 512 + cc] = acc[mf][nf][r] + bias[cc];
      }
#undef STAGE_AB
}

// ---------------- sliding-window attention v9 --------------------------
// v7 (dual q-tile ILP, swapped-QK in-reg softmax, swizzled V-LDS) with the
// K operand moved from direct global loads (HBM latency on the critical
// path every iteration) to a 3-buffer DMA ring staged 2 iterations ahead
// with counted vmcnt — the mechanism proven in k_gemm_out. K tile = 4KB
// [32 keys][64 d], XOR-swizzled via pre-swizzled DMA source (rule #21).
__global__ __launch_bounds__(256, 2) void k_attn(
    const ushort* __restrict__ qp, const ushort* __restrict__ kp,
    const ushort* __restrict__ vp, ushort* __restrict__ ctx)
{
  const int E = 512, SEQ = 4096;
  int bid0 = blockIdx.x;
  int bid = (bid0 & 7) * 60 + (bid0 >> 3);   // XCD-chunked (480 % 8 == 0)
  int qh = bid & 1;
  int h = (bid >> 1) & 7;
  int n = (bid >> 4) % 15;
  int b = bid / 240;
  int start = n * 256;

  int tid = threadIdx.x;
  int w = tid >> 6, ln = tid & 63;
  int l31 = ln & 31, hi = ln >> 5;

  size_t base = ((size_t)(b * SEQ + start)) * E + h * 64;
  const ushort* Kw = kp + base;
  const ushort* Vw = vp + base;
  const ushort* Qw = qp + base;

  __shared__ ushort Vt[32768];     // 64KB V^T, byte^=(d&7)<<4
  __shared__ ushort Ks[3][2048];   // 12KB K ring, byte^=(row&7)<<4

  // ---- stage V transposed (unchanged v7) ----
  {
    int sk = (tid & 63) * 8;
    int sd = (tid >> 6) * 16;
    const ushort* src = Vw + (size_t)sk * E + sd;
    union { uint4 q[2]; ushort u[16]; } R0, R1, R2, R3, R4, R5, R6, R7;
    R0.q[0] = *(const uint4*)(src + 0 * E); R0.q[1] = *(const uint4*)(src + 0 * E + 8);
    R1.q[0] = *(const uint4*)(src + 1 * E); R1.q[1] = *(const uint4*)(src + 1 * E + 8);
    R2.q[0] = *(const uint4*)(src + 2 * E); R2.q[1] = *(const uint4*)(src + 2 * E + 8);
    R3.q[0] = *(const uint4*)(src + 3 * E); R3.q[1] = *(const uint4*)(src + 3 * E + 8);
    R4.q[0] = *(const uint4*)(src + 4 * E); R4.q[1] = *(const uint4*)(src + 4 * E + 8);
    R5.q[0] = *(const uint4*)(src + 5 * E); R5.q[1] = *(const uint4*)(src + 5 * E + 8);
    R6.q[0] = *(const uint4*)(src + 6 * E); R6.q[1] = *(const uint4*)(src + 6 * E + 8);
    R7.q[0] = *(const uint4*)(src + 7 * E); R7.q[1] = *(const uint4*)(src + 7 * E + 8);
#pragma unroll
    for (int d0 = 0; d0 < 16; ++d0) {
      int d = sd + d0;
      uint4 val;
      val.x = (uint)R0.u[d0] | ((uint)R1.u[d0] << 16);
      val.y = (uint)R2.u[d0] | ((uint)R3.u[d0] << 16);
      val.z = (uint)R4.u[d0] | ((uint)R5.u[d0] << 16);
      val.w = (uint)R6.u[d0] | ((uint)R7.u[d0] << 16);
      int off = d * 1024 + ((sk * 2) ^ ((d & 7) << 4));
      *(uint4*)((char*)Vt + off) = val;
    }
  }
  __syncthreads();

  int q0 = qh * 256 + w * 64;

  bf16x8 qa0, qa1, qa2, qa3, qb0, qb1, qb2, qb3;
  {
    const ushort* qra = Qw + (size_t)(q0 + l31) * E + hi * 8;
    const ushort* qrb = qra + (size_t)32 * E;
    qa0 = *reinterpret_cast<const bf16x8*>(qra + 0);
    qa1 = *reinterpret_cast<const bf16x8*>(qra + 16);
    qa2 = *reinterpret_cast<const bf16x8*>(qra + 32);
    qa3 = *reinterpret_cast<const bf16x8*>(qra + 48);
    qb0 = *reinterpret_cast<const bf16x8*>(qrb + 0);
    qb1 = *reinterpret_cast<const bf16x8*>(qrb + 16);
    qb2 = *reinterpret_cast<const bf16x8*>(qrb + 32);
    qb3 = *reinterpret_cast<const bf16x8*>(qrb + 48);
  }

  // K ring staging: thread t owns row t>>3, 16B slot (t&7)*16 within the
  // 128B row; DMA source pre-swizzled so LDS is linear, reads XOR-swizzle.
#define STAGE_K(KB, BUF)                                                      \
  {                                                                           \
    int row_ = tid >> 3;                                                      \
    int cs_ = (tid & 7) * 16;                                                 \
    int del_ = (cs_ ^ ((row_ & 7) << 4)) >> 1;                                \
    gld_lds16(Kw + (size_t)((KB) * 32 + row_) * E + del_,                     \
              (char*)&Ks[BUF][0] + tid * 16);                                 \
  }

  f32x16 ca0 = {}, ca1 = {}, cb0_ = {}, cb1_ = {};
  float psa = 0.f, psb = 0.f;
  const char* lb = (const char*)Vt;

  STAGE_K(0, 0);
  STAGE_K(1, 1);
  VMW1; SCHEDB;     // K0 done; K1 in flight
  RBAR;

#pragma unroll
  for (int kb = 0; kb < 16; ++kb) {
    if (kb < 14) STAGE_K(kb + 2, (kb + 2) % 3);

    bf16x8 kf0, kf1, kf2, kf3;
    {
      const char* kbase = (const char*)&Ks[kb % 3][0] + l31 * 128;
      int xr = (l31 & 7) << 4;
      kf0 = *reinterpret_cast<const bf16x8*>(kbase + ((0 * 32 + hi * 16) ^ xr));
      kf1 = *reinterpret_cast<const bf16x8*>(kbase + ((1 * 32 + hi * 16) ^ xr));
      kf2 = *reinterpret_cast<const bf16x8*>(kbase + ((2 * 32 + hi * 16) ^ xr));
      kf3 = *reinterpret_cast<const bf16x8*>(kbase + ((3 * 32 + hi * 16) ^ xr));
    }
    bf16x8 vb0, vb1, vb2, vb3;
    {
      int row = l31, rowh = 32 + l31;
      int cb0 = kb * 64 + hi * 16;
      int cb1 = cb0 + 32;
      int xr0 = (row & 7) << 4;
      vb0 = *reinterpret_cast<const bf16x8*>(lb + row * 1024 + (cb0 ^ xr0));
      vb1 = *reinterpret_cast<const bf16x8*>(lb + rowh * 1024 + (cb0 ^ xr0));
      vb2 = *reinterpret_cast<const bf16x8*>(lb + row * 1024 + (cb1 ^ xr0));
      vb3 = *reinterpret_cast<const bf16x8*>(lb + rowh * 1024 + (cb1 ^ xr0));
    }

    f32x16 s1 = {}, s2 = {};
    __builtin_amdgcn_s_setprio(1);
    s1 = __builtin_amdgcn_mfma_f32_32x32x16_bf16(kf0, qa0, s1, 0, 0, 0);
    s2 = __builtin_amdgcn_mfma_f32_32x32x16_bf16(kf0, qb0, s2, 0, 0, 0);
    s1 = __builtin_amdgcn_mfma_f32_32x32x16_bf16(kf1, qa1, s1, 0, 0, 0);
    s2 = __builtin_amdgcn_mfma_f32_32x32x16_bf16(kf1, qb1, s2, 0, 0, 0);
    s1 = __builtin_amdgcn_mfma_f32_32x32x16_bf16(kf2, qa2, s1, 0, 0, 0);
    s2 = __builtin_amdgcn_mfma_f32_32x32x16_bf16(kf2, qb2, s2, 0, 0, 0);
    s1 = __builtin_amdgcn_mfma_f32_32x32x16_bf16(kf3, qa3, s1, 0, 0, 0);
    s2 = __builtin_amdgcn_mfma_f32_32x32x16_bf16(kf3, qb3, s2, 0, 0, 0);
    __builtin_amdgcn_s_setprio(0);

#pragma unroll
    for (int r = 0; r < 16; ++r) s1[r] = __builtin_amdgcn_exp2f(s1[r]);
#pragma unroll
    for (int r = 0; r < 16; ++r) s2[r] = __builtin_amdgcn_exp2f(s2[r]);
    {
      float t0 = (s1[0] + s1[1]) + (s1[2] + s1[3]);
      float t1 = (s1[4] + s1[5]) + (s1[6] + s1[7]);
      float t2 = (s1[8] + s1[9]) + (s1[10] + s1[11]);
      float t3 = (s1[12] + s1[13]) + (s1[14] + s1[15]);
      psa += (t0 + t1) + (t2 + t3);
      float u0 = (s2[0] + s2[1]) + (s2[2] + s2[3]);
      float u1 = (s2[4] + s2[5]) + (s2[6] + s2[7]);
      float u2 = (s2[8] + s2[9]) + (s2[10] + s2[11]);
      float u3 = (s2[12] + s2[13]) + (s2[14] + s2[15]);
      psb += (u0 + u1) + (u2 + u3);
    }

    uint a0, a1, a2, a3, a4, a5, a6, a7;
    asm("v_cvt_pk_bf16_f32 %0, %1, %2" : "=v"(a0) : "v"(s1[0]),  "v"(s1[1]));
    asm("v_cvt_pk_bf16_f32 %0, %1, %2" : "=v"(a1) : "v"(s1[2]),  "v"(s1[3]));
    asm("v_cvt_pk_bf16_f32 %0, %1, %2" : "=v"(a2) : "v"(s1[4]),  "v"(s1[5]));
    asm("v_cvt_pk_bf16_f32 %0, %1, %2" : "=v"(a3) : "v"(s1[6]),  "v"(s1[7]));
    asm("v_cvt_pk_bf16_f32 %0, %1, %2" : "=v"(a4) : "v"(s1[8]),  "v"(s1[9]));
    asm("v_cvt_pk_bf16_f32 %0, %1, %2" : "=v"(a5) : "v"(s1[10]), "v"(s1[11]));
    asm("v_cvt_pk_bf16_f32 %0, %1, %2" : "=v"(a6) : "v"(s1[12]), "v"(s1[13]));
    asm("v_cvt_pk_bf16_f32 %0, %1, %2" : "=v"(a7) : "v"(s1[14]), "v"(s1[15]));
    asm("v_permlane32_swap_b32 %0, %1" : "+v"(a0), "+v"(a2));
    asm("v_permlane32_swap_b32 %0, %1" : "+v"(a1), "+v"(a3));
    asm("v_permlane32_swap_b32 %0, %1" : "+v"(a4), "+v"(a6));
    asm("v_permlane32_swap_b32 %0, %1" : "+v"(a5), "+v"(a7));
    uint b0, b1, b2, b3, b4, b5, b6, b7;
    asm("v_cvt_pk_bf16_f32 %0, %1, %2" : "=v"(b0) : "v"(s2[0]),  "v"(s2[1]));
    asm("v_cvt_pk_bf16_f32 %0, %1, %2" : "=v"(b1) : "v"(s2[2]),  "v"(s2[3]));
    asm("v_cvt_pk_bf16_f32 %0, %1, %2" : "=v"(b2) : "v"(s2[4]),  "v"(s2[5]));
    asm("v_cvt_pk_bf16_f32 %0, %1, %2" : "=v"(b3) : "v"(s2[6]),  "v"(s2[7]));
    asm("v_cvt_pk_bf16_f32 %0, %1, %2" : "=v"(b4) : "v"(s2[8]),  "v"(s2[9]));
    asm("v_cvt_pk_bf16_f32 %0, %1, %2" : "=v"(b5) : "v"(s2[10]), "v"(s2[11]));
    asm("v_cvt_pk_bf16_f32 %0, %1, %2" : "=v"(b6) : "v"(s2[12]), "v"(s2[13]));
    asm("v_cvt_pk_bf16_f32 %0, %1, %2" : "=v"(b7) : "v"(s2[14]), "v"(s2[15]));
    asm("v_permlane32_swap_b32 %0, %1" : "+v"(b0), "+v"(b2));
    asm("v_permlane32_swap_b32 %0, %1" : "+v"(b1), "+v"(b3));
    asm("v_permlane32_swap_b32 %0, %1" : "+v"(b4), "+v"(b6));
    asm("v_permlane32_swap_b32 %0, %1" : "+v"(b5), "+v"(b7));
    union { uint u[4]; bf16x8 v; } A1, A2, B1, B2;
    A1.u[0] = a0; A1.u[1] = a1; A1.u[2] = a2; A1.u[3] = a3;
    A2.u[0] = a4; A2.u[1] = a5; A2.u[2] = a6; A2.u[3] = a7;
    B1.u[0] = b0; B1.u[1] = b1; B1.u[2] = b2; B1.u[3] = b3;
    B2.u[0] = b4; B2.u[1] = b5; B2.u[2] = b6; B2.u[3] = b7;

    __builtin_amdgcn_s_setprio(1);
    ca0  = __builtin_amdgcn_mfma_f32_32x32x16_bf16(A1.v, vb0, ca0, 0, 0, 0);
    cb0_ = __builtin_amdgcn_mfma_f32_32x32x16_bf16(B1.v, vb0, cb0_, 0, 0, 0);
    ca1  = __builtin_amdgcn_mfma_f32_32x32x16_bf16(A1.v, vb1, ca1, 0, 0, 0);
    cb1_ = __builtin_amdgcn_mfma_f32_32x32x16_bf16(B1.v, vb1, cb1_, 0, 0, 0);
    ca0  = __builtin_amdgcn_mfma_f32_32x32x16_bf16(A2.v, vb2, ca0, 0, 0, 0);
    cb0_ = __builtin_amdgcn_mfma_f32_32x32x16_bf16(B2.v, vb2, cb0_, 0, 0, 0);
    ca1  = __builtin_amdgcn_mfma_f32_32x32x16_bf16(A2.v, vb3, ca1, 0, 0, 0);
    cb1_ = __builtin_amdgcn_mfma_f32_32x32x16_bf16(B2.v, vb3, cb1_, 0, 0, 0);
    __builtin_amdgcn_s_setprio(0);

    if (kb < 15) {
      if (kb < 14) { VMW1; } else { VMW0; }
      SCHEDB;
      RBAR;
    }
  }
#undef STAGE_K

  psa += __shfl_xor(psa, 32);
  psb += __shfl_xor(psb, 32);
  float ria = 1.0f / psa;
  float rib = 1.0f / psb;
  size_t orow0 = (size_t)b * 7680 + (size_t)n * 512 + q0;
#pragma unroll
  for (int r = 0; r < 16; ++r) {
    int qrel = (r & 3) + 8 * (r >> 2) + 4 * hi;
    float r1 = __shfl(ria, qrel);
    float r2 = __shfl(rib, qrel);
    ushort* dA = ctx + (orow0 + qrel) * E + h * 64 + l31;
    ushort* dB = ctx + (orow0 + 32 + qrel) * E + h * 64 + l31;
    dA[0]  = f2bf(ca0[r] * r1);
    dA[32] = f2bf(ca1[r] * r1);
    dB[0]  = f2bf(cb0_[r] * r2);
    dB[32] = f2bf(cb1_[r] * r2);
  }
}

// ---------------- launch ----------------
extern "C" void kernel_launch(void* const* d_in, const int* in_sizes, int n_in,
                              void* d_out, int out_size, void* d_ws, size_t ws_size,
                              hipStream_t stream) {
  const float* query = (const float*)d_in[0];
  const float* key   = (const float*)d_in[1];
  const float* value = (const float*)d_in[2];
  const float* ipw   = (const float*)d_in[3];
  const float* ipb   = (const float*)d_in[4];
  const float* opw   = (const float*)d_in[5];
  const float* opb   = (const float*)d_in[6];

  // workspace layout (ushort elements)
  ushort* wib = (ushort*)d_ws;       // in_proj_weight bf16 (1536x512)
  ushort* wob = wib + 786432;        // out_proj_weight bf16 (512x512)
  ushort* qp  = wob + 262144;        // projected q (2,4096,512)
  ushort* kp  = qp  + 4194304;
  ushort* vp  = kp  + 4194304;
  ushort* ctx = vp  + 4194304;       // (2,7680,512)

  const float SC = 0.125f * 1.44269504088896340736f;

  k_cvt_w<<<512, 256, 0, stream>>>(ipw, opw, wib);

  k_gemm_qkv<<<768, 256, 0, stream>>>(
      query, key, value, wib, ipb, qp, SC);

  k_attn<<<480, 256, 0, stream>>>(qp, kp, vp, ctx);

  k_gemm_out<<<480, 256, 0, stream>>>(
      ctx, wob, opb, (float*)d_out);
}

// Round 20
// 81.491 us; speedup vs baseline: 2.3746x; 2.3746x over previous
//
#include <hip/hip_runtime.h>
#include <hip/hip_bf16.h>

typedef __bf16 bf16x8 __attribute__((ext_vector_type(8)));
typedef float f32x4 __attribute__((ext_vector_type(4)));
typedef float f32x16 __attribute__((ext_vector_type(16)));

__device__ __forceinline__ ushort f2bf(float f) {
  union { float f; unsigned u; } x; x.f = f;
  unsigned r = x.u + 0x7fffu + ((x.u >> 16) & 1u);
  return (ushort)(r >> 16);
}

__device__ __forceinline__ void gld_lds16(const void* g, void* l) {
  __builtin_amdgcn_global_load_lds(
      (const __attribute__((address_space(1))) void*)g,
      (__attribute__((address_space(3))) void*)l, 16, 0, 0);
}

#define VMW2   asm volatile("s_waitcnt vmcnt(2)" ::: "memory")
#define VMW4   asm volatile("s_waitcnt vmcnt(4)" ::: "memory")
#define VMW0   asm volatile("s_waitcnt vmcnt(0)" ::: "memory")
#define LGKM0  asm volatile("s_waitcnt lgkmcnt(0)" ::: "memory")
#define SCHEDB __builtin_amdgcn_sched_barrier(0)
#define RBAR   __builtin_amdgcn_s_barrier()

// ---------------- f32 -> bf16 convert (weights only) ----------------
__global__ __launch_bounds__(256) void k_cvt_w(
    const float* __restrict__ wi, const float* __restrict__ wo,
    ushort* __restrict__ dst) {
  const int NWI = 196608, NWO = 65536;   // float4 counts
  const int total = NWI + NWO;
  int i = blockIdx.x * 256 + threadIdx.x;
  int stride = gridDim.x * 256;
  for (; i < total; i += stride) {
    const float* s; int j;
    if (i < NWI) { s = wi; j = i; }
    else         { s = wo; j = i - NWI; }
    float4 val = reinterpret_cast<const float4*>(s)[j];
    ushort4 o;
    o.x = f2bf(val.x); o.y = f2bf(val.y); o.z = f2bf(val.z); o.w = f2bf(val.w);
    reinterpret_cast<ushort4*>(dst)[i] = o;
  }
}

// ---------------- QKV GEMM: counted-vmcnt pipeline (R13 proven) ----------
// C[z] = cvt_bf16(Az) @ W[z]^T + bias. 128x128 tile, BK=32, 4 waves.
// B: 3 LDS buffers, DMA issued 2 tiles ahead, left IN FLIGHT across the
// raw s_barrier (counted vmcnt(2) waits only the needed tile). A: f32 ->
// regs -> cvt_pk -> ds_write, 2 buffers.
__global__ __launch_bounds__(256) void k_gemm_qkv(
    const float* __restrict__ za0, const float* __restrict__ za1,
    const float* __restrict__ za2,
    const ushort* __restrict__ Btbase,
    const float* __restrict__ biasbase,
    ushort* __restrict__ Cbase, float qs)
{
  int bid0 = blockIdx.x;
  int bid = (bid0 & 7) * 96 + (bid0 >> 3);   // XCD-chunked, 768 % 8 == 0
  int yy = bid & 3;
  int rest = bid >> 2;
  int xx = rest & 63;
  int z = rest >> 6;

  const float* A32 = (z == 0) ? za0 : (z == 1) ? za1 : za2;
  const ushort* Bt = Btbase + (size_t)262144 * z;
  const float* bias = biasbase + 512 * z;
  float osc = (z == 0) ? qs : 1.0f;

  __shared__ ushort As[2][4096];   // 16KB
  __shared__ ushort Bs[3][4096];   // 24KB

  int tid = threadIdx.x;
  int wv = tid >> 6, ln = tid & 63;
  int l15 = ln & 15, lg = ln >> 4;
  int wm = wv >> 1, wn = wv & 1;
  int m0 = xx * 128, n0 = yy * 128;

  int row_s = tid >> 1, kh = (tid & 1) * 16;
  const float* aP = A32 + (size_t)(m0 + row_s) * 512 + kh;
  int ldsOff = row_s * 32 + kh;

#define STAGE_B(KT, BUF)                                                      \
  {                                                                           \
    _Pragma("unroll")                                                         \
    for (int h2 = 0; h2 < 2; ++h2) {                                          \
      int c = h2 * 256 + wv * 64 + ln;                                        \
      int row = c >> 2, kc = (c & 3) * 8;                                     \
      gld_lds16(Bt + (size_t)(n0 + row) * 512 + (KT) * 32 + kc,               \
                (char*)&Bs[BUF][0] + (h2 * 256 + wv * 64) * 16);              \
    }                                                                         \
  }

#define CVT_WRITE_A(F0, F1, F2, F3, BUF)                                      \
  {                                                                           \
    uint w0, w1, w2, w3, w4, w5, w6, w7;                                      \
    asm("v_cvt_pk_bf16_f32 %0, %1, %2" : "=v"(w0) : "v"(F0.x), "v"(F0.y));    \
    asm("v_cvt_pk_bf16_f32 %0, %1, %2" : "=v"(w1) : "v"(F0.z), "v"(F0.w));    \
    asm("v_cvt_pk_bf16_f32 %0, %1, %2" : "=v"(w2) : "v"(F1.x), "v"(F1.y));    \
    asm("v_cvt_pk_bf16_f32 %0, %1, %2" : "=v"(w3) : "v"(F1.z), "v"(F1.w));    \
    asm("v_cvt_pk_bf16_f32 %0, %1, %2" : "=v"(w4) : "v"(F2.x), "v"(F2.y));    \
    asm("v_cvt_pk_bf16_f32 %0, %1, %2" : "=v"(w5) : "v"(F2.z), "v"(F2.w));    \
    asm("v_cvt_pk_bf16_f32 %0, %1, %2" : "=v"(w6) : "v"(F3.x), "v"(F3.y));    \
    asm("v_cvt_pk_bf16_f32 %0, %1, %2" : "=v"(w7) : "v"(F3.z), "v"(F3.w));    \
    uint4 p0; p0.x = w0; p0.y = w1; p0.z = w2; p0.w = w3;                     \
    uint4 p1; p1.x = w4; p1.y = w5; p1.z = w6; p1.w = w7;                     \
    reinterpret_cast<uint4*>(&As[BUF][ldsOff])[0] = p0;                       \
    reinterpret_cast<uint4*>(&As[BUF][ldsOff + 8])[0] = p1;                   \
  }

  f32x4 acc[4][4] = {};

  // prologue: B(0), A(0), B(1); wait B(0)+A(0) (leave B(1) in flight)
  STAGE_B(0, 0);
  float4 g0 = reinterpret_cast<const float4*>(aP)[0];
  float4 g1 = reinterpret_cast<const float4*>(aP)[1];
  float4 g2 = reinterpret_cast<const float4*>(aP)[2];
  float4 g3 = reinterpret_cast<const float4*>(aP)[3];
  STAGE_B(1, 1);
  VMW2; SCHEDB;
  CVT_WRITE_A(g0, g1, g2, g3, 0);
  LGKM0; SCHEDB;
  RBAR;

#pragma unroll
  for (int kt = 0; kt < 16; ++kt) {
    const int cur = kt & 1;
    const int bcur = kt % 3;
    float4 f0, f1, f2, f3;
    if (kt < 15) {
      const float* ap = aP + (kt + 1) * 32;
      f0 = reinterpret_cast<const float4*>(ap)[0];
      f1 = reinterpret_cast<const float4*>(ap)[1];
      f2 = reinterpret_cast<const float4*>(ap)[2];
      f3 = reinterpret_cast<const float4*>(ap)[3];
    }
    if (kt < 14) STAGE_B(kt + 2, (kt + 2) % 3);

    bf16x8 af[4], bf4[4];
#pragma unroll
    for (int mf = 0; mf < 4; ++mf)
      af[mf] = *reinterpret_cast<const bf16x8*>(&As[cur][(wm * 64 + mf * 16 + l15) * 32 + lg * 8]);
#pragma unroll
    for (int nf = 0; nf < 4; ++nf)
      bf4[nf] = *reinterpret_cast<const bf16x8*>(&Bs[bcur][(wn * 64 + nf * 16 + l15) * 32 + lg * 8]);
#pragma unroll
    for (int mf = 0; mf < 4; ++mf)
#pragma unroll
      for (int nf = 0; nf < 4; ++nf)
        acc[mf][nf] = __builtin_amdgcn_mfma_f32_16x16x32_bf16(af[mf], bf4[nf], acc[mf][nf], 0, 0, 0);

    if (kt < 15) {
      if (kt < 14) { VMW2; } else { VMW0; }
      SCHEDB;
      CVT_WRITE_A(f0, f1, f2, f3, cur ^ 1);
      LGKM0; SCHEDB;
      RBAR;
    }
  }

#pragma unroll
  for (int mf = 0; mf < 4; ++mf)
#pragma unroll
    for (int nf = 0; nf < 4; ++nf)
#pragma unroll
      for (int r = 0; r < 4; ++r) {
        int rr = m0 + wm * 64 + mf * 16 + lg * 4 + r;
        int cc = n0 + wn * 64 + nf * 16 + l15;
        float v = (acc[mf][nf][r] + bias[cc]) * osc;
        (Cbase + (size_t)4194304 * z)[(size_t)rr * 512 + cc] = f2bf(v);
      }
#undef STAGE_B
#undef CVT_WRITE_A
}

// ---------------- out-proj GEMM: counted-vmcnt pipeline (bf16 A) ----------
__global__ __launch_bounds__(256) void k_gemm_out(
    const ushort* __restrict__ Ab, const ushort* __restrict__ Bt,
    const float* __restrict__ bias, float* __restrict__ C)
{
  int bid0 = blockIdx.x;
  int bid = (bid0 & 7) * 60 + (bid0 >> 3);   // XCD-chunked, 480 % 8 == 0
  int yy = bid & 3;
  int xx = bid >> 2;

  __shared__ ushort As[3][4096];   // 24KB
  __shared__ ushort Bs[3][4096];   // 24KB

  int tid = threadIdx.x;
  int wv = tid >> 6, ln = tid & 63;
  int l15 = ln & 15, lg = ln >> 4;
  int wm = wv >> 1, wn = wv & 1;
  int m0 = xx * 128, n0 = yy * 128;

#define STAGE_AB(KT, BUF)                                                     \
  {                                                                           \
    _Pragma("unroll")                                                         \
    for (int h2 = 0; h2 < 2; ++h2) {                                          \
      int c = h2 * 256 + wv * 64 + ln;                                        \
      int row = c >> 2, kc = (c & 3) * 8;                                     \
      gld_lds16(Ab + (size_t)(m0 + row) * 512 + (KT) * 32 + kc,               \
                (char*)&As[BUF][0] + (h2 * 256 + wv * 64) * 16);              \
      gld_lds16(Bt + (size_t)(n0 + row) * 512 + (KT) * 32 + kc,               \
                (char*)&Bs[BUF][0] + (h2 * 256 + wv * 64) * 16);              \
    }                                                                         \
  }

  f32x4 acc[4][4] = {};

  STAGE_AB(0, 0);
  STAGE_AB(1, 1);
  VMW4; SCHEDB;   // tile0's 4 DMAs done, tile1's 4 in flight
  RBAR;

#pragma unroll
  for (int kt = 0; kt < 16; ++kt) {
    const int bcur = kt % 3;
    if (kt < 14) STAGE_AB(kt + 2, (kt + 2) % 3);

    bf16x8 af[4], bf4[4];
#pragma unroll
    for (int mf = 0; mf < 4; ++mf)
      af[mf] = *reinterpret_cast<const bf16x8*>(&As[bcur][(wm * 64 + mf * 16 + l15) * 32 + lg * 8]);
#pragma unroll
    for (int nf = 0; nf < 4; ++nf)
      bf4[nf] = *reinterpret_cast<const bf16x8*>(&Bs[bcur][(wn * 64 + nf * 16 + l15) * 32 + lg * 8]);
#pragma unroll
    for (int mf = 0; mf < 4; ++mf)
#pragma unroll
      for (int nf = 0; nf < 4; ++nf)
        acc[mf][nf] = __builtin_amdgcn_mfma_f32_16x16x32_bf16(af[mf], bf4[nf], acc[mf][nf], 0, 0, 0);

    if (kt < 15) {
      if (kt < 14) { VMW4; } else { VMW0; }
      SCHEDB;
      RBAR;
    }
  }

#pragma unroll
  for (int mf = 0; mf < 4; ++mf)
#pragma unroll
    for (int nf = 0; nf < 4; ++nf)
#pragma unroll
      for (int r = 0; r < 4; ++r) {
        int rr = m0 + wm * 64 + mf * 16 + lg * 4 + r;
        int cc = n0 + wn * 64 + nf * 16 + l15;
        C[(size_t)rr * 512 + cc] = acc[mf][nf][r] + bias[cc];
      }
#undef STAGE_AB
}

// ---------------- sliding-window attention v7 (2 q-tiles/wave ILP) --------
// 480 blocks (b,n,h,qhalf) x 4 waves; each wave owns 64 q-rows as TWO
// independent 32-row tiles sharing K-frag loads + V ds_reads. Full V
// staged once in 64KB swizzled LDS. Proven local optimum (R18 split-d and
// R19 K-DMA-ring both regressed: duplicated work / register spill).
__global__ __launch_bounds__(256, 2) void k_attn(
    const ushort* __restrict__ qp, const ushort* __restrict__ kp,
    const ushort* __restrict__ vp, ushort* __restrict__ ctx)
{
  const int E = 512, SEQ = 4096;
  int bid0 = blockIdx.x;
  int bid = (bid0 & 7) * 60 + (bid0 >> 3);   // XCD-chunked (480 % 8 == 0)
  int qh = bid & 1;
  int h = (bid >> 1) & 7;
  int n = (bid >> 4) % 15;
  int b = bid / 240;
  int start = n * 256;

  int tid = threadIdx.x;
  int w = tid >> 6, ln = tid & 63;
  int l31 = ln & 31, hi = ln >> 5;

  size_t base = ((size_t)(b * SEQ + start)) * E + h * 64;
  const ushort* Kw = kp + base;
  const ushort* Vw = vp + base;
  const ushort* Qw = qp + base;

  __shared__ ushort Vt[32768];  // Vt[d=64][k=512], 64KB, byte^=(d&7)<<4

  // ---- stage V transposed: thread t owns 8 keys x 16 d ----
  {
    int sk = (tid & 63) * 8;
    int sd = (tid >> 6) * 16;
    const ushort* src = Vw + (size_t)sk * E + sd;
    union { uint4 q[2]; ushort u[16]; } R0, R1, R2, R3, R4, R5, R6, R7;
    R0.q[0] = *(const uint4*)(src + 0 * E); R0.q[1] = *(const uint4*)(src + 0 * E + 8);
    R1.q[0] = *(const uint4*)(src + 1 * E); R1.q[1] = *(const uint4*)(src + 1 * E + 8);
    R2.q[0] = *(const uint4*)(src + 2 * E); R2.q[1] = *(const uint4*)(src + 2 * E + 8);
    R3.q[0] = *(const uint4*)(src + 3 * E); R3.q[1] = *(const uint4*)(src + 3 * E + 8);
    R4.q[0] = *(const uint4*)(src + 4 * E); R4.q[1] = *(const uint4*)(src + 4 * E + 8);
    R5.q[0] = *(const uint4*)(src + 5 * E); R5.q[1] = *(const uint4*)(src + 5 * E + 8);
    R6.q[0] = *(const uint4*)(src + 6 * E); R6.q[1] = *(const uint4*)(src + 6 * E + 8);
    R7.q[0] = *(const uint4*)(src + 7 * E); R7.q[1] = *(const uint4*)(src + 7 * E + 8);
#pragma unroll
    for (int d0 = 0; d0 < 16; ++d0) {
      int d = sd + d0;
      uint4 val;
      val.x = (uint)R0.u[d0] | ((uint)R1.u[d0] << 16);
      val.y = (uint)R2.u[d0] | ((uint)R3.u[d0] << 16);
      val.z = (uint)R4.u[d0] | ((uint)R5.u[d0] << 16);
      val.w = (uint)R6.u[d0] | ((uint)R7.u[d0] << 16);
      int off = d * 1024 + ((sk * 2) ^ ((d & 7) << 4));
      *(uint4*)((char*)Vt + off) = val;
    }
  }
  __syncthreads();

  int q0 = qh * 256 + w * 64;

  bf16x8 qa0, qa1, qa2, qa3, qb0, qb1, qb2, qb3;
  {
    const ushort* qra = Qw + (size_t)(q0 + l31) * E + hi * 8;
    const ushort* qrb = qra + (size_t)32 * E;
    qa0 = *reinterpret_cast<const bf16x8*>(qra + 0);
    qa1 = *reinterpret_cast<const bf16x8*>(qra + 16);
    qa2 = *reinterpret_cast<const bf16x8*>(qra + 32);
    qa3 = *reinterpret_cast<const bf16x8*>(qra + 48);
    qb0 = *reinterpret_cast<const bf16x8*>(qrb + 0);
    qb1 = *reinterpret_cast<const bf16x8*>(qrb + 16);
    qb2 = *reinterpret_cast<const bf16x8*>(qrb + 32);
    qb3 = *reinterpret_cast<const bf16x8*>(qrb + 48);
  }

  f32x16 ca0 = {}, ca1 = {}, cb0_ = {}, cb1_ = {};
  float psa = 0.f, psb = 0.f;
  const char* lb = (const char*)Vt;

#pragma unroll
  for (int kb = 0; kb < 16; ++kb) {
    bf16x8 kf0, kf1, kf2, kf3;
    {
      const ushort* kr = Kw + (size_t)(kb * 32 + l31) * E + hi * 8;
      kf0 = *reinterpret_cast<const bf16x8*>(kr + 0);
      kf1 = *reinterpret_cast<const bf16x8*>(kr + 16);
      kf2 = *reinterpret_cast<const bf16x8*>(kr + 32);
      kf3 = *reinterpret_cast<const bf16x8*>(kr + 48);
    }
    bf16x8 vb00, vb01, vb10, vb11;
    {
      int row = l31, rowh = 32 + l31;
      int cb0 = kb * 64 + hi * 16;
      int cb1 = cb0 + 32;
      int xr0 = (row & 7) << 4;
      vb00 = *reinterpret_cast<const bf16x8*>(lb + row * 1024 + (cb0 ^ xr0));
      vb01 = *reinterpret_cast<const bf16x8*>(lb + rowh * 1024 + (cb0 ^ xr0));
      vb10 = *reinterpret_cast<const bf16x8*>(lb + row * 1024 + (cb1 ^ xr0));
      vb11 = *reinterpret_cast<const bf16x8*>(lb + rowh * 1024 + (cb1 ^ xr0));
    }

    f32x16 s1 = {}, s2 = {};
    __builtin_amdgcn_s_setprio(1);
    s1 = __builtin_amdgcn_mfma_f32_32x32x16_bf16(kf0, qa0, s1, 0, 0, 0);
    s2 = __builtin_amdgcn_mfma_f32_32x32x16_bf16(kf0, qb0, s2, 0, 0, 0);
    s1 = __builtin_amdgcn_mfma_f32_32x32x16_bf16(kf1, qa1, s1, 0, 0, 0);
    s2 = __builtin_amdgcn_mfma_f32_32x32x16_bf16(kf1, qb1, s2, 0, 0, 0);
    s1 = __builtin_amdgcn_mfma_f32_32x32x16_bf16(kf2, qa2, s1, 0, 0, 0);
    s2 = __builtin_amdgcn_mfma_f32_32x32x16_bf16(kf2, qb2, s2, 0, 0, 0);
    s1 = __builtin_amdgcn_mfma_f32_32x32x16_bf16(kf3, qa3, s1, 0, 0, 0);
    s2 = __builtin_amdgcn_mfma_f32_32x32x16_bf16(kf3, qb3, s2, 0, 0, 0);
    __builtin_amdgcn_s_setprio(0);

#pragma unroll
    for (int r = 0; r < 16; ++r) s1[r] = __builtin_amdgcn_exp2f(s1[r]);
#pragma unroll
    for (int r = 0; r < 16; ++r) s2[r] = __builtin_amdgcn_exp2f(s2[r]);
    {
      float t0 = (s1[0] + s1[1]) + (s1[2] + s1[3]);
      float t1 = (s1[4] + s1[5]) + (s1[6] + s1[7]);
      float t2 = (s1[8] + s1[9]) + (s1[10] + s1[11]);
      float t3 = (s1[12] + s1[13]) + (s1[14] + s1[15]);
      psa += (t0 + t1) + (t2 + t3);
      float u0 = (s2[0] + s2[1]) + (s2[2] + s2[3]);
      float u1 = (s2[4] + s2[5]) + (s2[6] + s2[7]);
      float u2 = (s2[8] + s2[9]) + (s2[10] + s2[11]);
      float u3 = (s2[12] + s2[13]) + (s2[14] + s2[15]);
      psb += (u0 + u1) + (u2 + u3);
    }

    uint a0, a1, a2, a3, a4, a5, a6, a7;
    asm("v_cvt_pk_bf16_f32 %0, %1, %2" : "=v"(a0) : "v"(s1[0]),  "v"(s1[1]));
    asm("v_cvt_pk_bf16_f32 %0, %1, %2" : "=v"(a1) : "v"(s1[2]),  "v"(s1[3]));
    asm("v_cvt_pk_bf16_f32 %0, %1, %2" : "=v"(a2) : "v"(s1[4]),  "v"(s1[5]));
    asm("v_cvt_pk_bf16_f32 %0, %1, %2" : "=v"(a3) : "v"(s1[6]),  "v"(s1[7]));
    asm("v_cvt_pk_bf16_f32 %0, %1, %2" : "=v"(a4) : "v"(s1[8]),  "v"(s1[9]));
    asm("v_cvt_pk_bf16_f32 %0, %1, %2" : "=v"(a5) : "v"(s1[10]), "v"(s1[11]));
    asm("v_cvt_pk_bf16_f32 %0, %1, %2" : "=v"(a6) : "v"(s1[12]), "v"(s1[13]));
    asm("v_cvt_pk_bf16_f32 %0, %1, %2" : "=v"(a7) : "v"(s1[14]), "v"(s1[15]));
    asm("v_permlane32_swap_b32 %0, %1" : "+v"(a0), "+v"(a2));
    asm("v_permlane32_swap_b32 %0, %1" : "+v"(a1), "+v"(a3));
    asm("v_permlane32_swap_b32 %0, %1" : "+v"(a4), "+v"(a6));
    asm("v_permlane32_swap_b32 %0, %1" : "+v"(a5), "+v"(a7));
    uint b0, b1, b2, b3, b4, b5, b6, b7;
    asm("v_cvt_pk_bf16_f32 %0, %1, %2" : "=v"(b0) : "v"(s2[0]),  "v"(s2[1]));
    asm("v_cvt_pk_bf16_f32 %0, %1, %2" : "=v"(b1) : "v"(s2[2]),  "v"(s2[3]));
    asm("v_cvt_pk_bf16_f32 %0, %1, %2" : "=v"(b2) : "v"(s2[4]),  "v"(s2[5]));
    asm("v_cvt_pk_bf16_f32 %0, %1, %2" : "=v"(b3) : "v"(s2[6]),  "v"(s2[7]));
    asm("v_cvt_pk_bf16_f32 %0, %1, %2" : "=v"(b4) : "v"(s2[8]),  "v"(s2[9]));
    asm("v_cvt_pk_bf16_f32 %0, %1, %2" : "=v"(b5) : "v"(s2[10]), "v"(s2[11]));
    asm("v_cvt_pk_bf16_f32 %0, %1, %2" : "=v"(b6) : "v"(s2[12]), "v"(s2[13]));
    asm("v_cvt_pk_bf16_f32 %0, %1, %2" : "=v"(b7) : "v"(s2[14]), "v"(s2[15]));
    asm("v_permlane32_swap_b32 %0, %1" : "+v"(b0), "+v"(b2));
    asm("v_permlane32_swap_b32 %0, %1" : "+v"(b1), "+v"(b3));
    asm("v_permlane32_swap_b32 %0, %1" : "+v"(b4), "+v"(b6));
    asm("v_permlane32_swap_b32 %0, %1" : "+v"(b5), "+v"(b7));
    union { uint u[4]; bf16x8 v; } A1, A2, B1, B2;
    A1.u[0] = a0; A1.u[1] = a1; A1.u[2] = a2; A1.u[3] = a3;
    A2.u[0] = a4; A2.u[1] = a5; A2.u[2] = a6; A2.u[3] = a7;
    B1.u[0] = b0; B1.u[1] = b1; B1.u[2] = b2; B1.u[3] = b3;
    B2.u[0] = b4; B2.u[1] = b5; B2.u[2] = b6; B2.u[3] = b7;

    __builtin_amdgcn_s_setprio(1);
    ca0  = __builtin_amdgcn_mfma_f32_32x32x16_bf16(A1.v, vb00, ca0, 0, 0, 0);
    cb0_ = __builtin_amdgcn_mfma_f32_32x32x16_bf16(B1.v, vb00, cb0_, 0, 0, 0);
    ca1  = __builtin_amdgcn_mfma_f32_32x32x16_bf16(A1.v, vb01, ca1, 0, 0, 0);
    cb1_ = __builtin_amdgcn_mfma_f32_32x32x16_bf16(B1.v, vb01, cb1_, 0, 0, 0);
    ca0  = __builtin_amdgcn_mfma_f32_32x32x16_bf16(A2.v, vb10, ca0, 0, 0, 0);
    cb0_ = __builtin_amdgcn_mfma_f32_32x32x16_bf16(B2.v, vb10, cb0_, 0, 0, 0);
    ca1  = __builtin_amdgcn_mfma_f32_32x32x16_bf16(A2.v, vb11, ca1, 0, 0, 0);
    cb1_ = __builtin_amdgcn_mfma_f32_32x32x16_bf16(B2.v, vb11, cb1_, 0, 0, 0);
    __builtin_amdgcn_s_setprio(0);
  }

  psa += __shfl_xor(psa, 32);
  psb += __shfl_xor(psb, 32);
  float ria = 1.0f / psa;
  float rib = 1.0f / psb;
  size_t orow0 = (size_t)b * 7680 + (size_t)n * 512 + q0;
#pragma unroll
  for (int r = 0; r < 16; ++r) {
    int qrel = (r & 3) + 8 * (r >> 2) + 4 * hi;
    float r1 = __shfl(ria, qrel);
    float r2 = __shfl(rib, qrel);
    ushort* dA = ctx + (orow0 + qrel) * E + h * 64 + l31;
    ushort* dB = ctx + (orow0 + 32 + qrel) * E + h * 64 + l31;
    dA[0]  = f2bf(ca0[r] * r1);
    dA[32] = f2bf(ca1[r] * r1);
    dB[0]  = f2bf(cb0_[r] * r2);
    dB[32] = f2bf(cb1_[r] * r2);
  }
}

// ---------------- launch ----------------
extern "C" void kernel_launch(void* const* d_in, const int* in_sizes, int n_in,
                              void* d_out, int out_size, void* d_ws, size_t ws_size,
                              hipStream_t stream) {
  const float* query = (const float*)d_in[0];
  const float* key   = (const float*)d_in[1];
  const float* value = (const float*)d_in[2];
  const float* ipw   = (const float*)d_in[3];
  const float* ipb   = (const float*)d_in[4];
  const float* opw   = (const float*)d_in[5];
  const float* opb   = (const float*)d_in[6];

  // workspace layout (ushort elements)
  ushort* wib = (ushort*)d_ws;       // in_proj_weight bf16 (1536x512)
  ushort* wob = wib + 786432;        // out_proj_weight bf16 (512x512)
  ushort* qp  = wob + 262144;        // projected q (2,4096,512)
  ushort* kp  = qp  + 4194304;
  ushort* vp  = kp  + 4194304;
  ushort* ctx = vp  + 4194304;       // (2,7680,512)

  const float SC = 0.125f * 1.44269504088896340736f;  // fold scale*log2e into Q

  k_cvt_w<<<512, 256, 0, stream>>>(ipw, opw, wib);

  k_gemm_qkv<<<768, 256, 0, stream>>>(
      query, key, value, wib, ipb, qp, SC);

  k_attn<<<480, 256, 0, stream>>>(qp, kp, vp, ctx);

  k_gemm_out<<<480, 256, 0, stream>>>(
      ctx, wob, opb, (float*)d_out);
}